// Round 3
// baseline (124.525 us; speedup 1.0000x reference)
//
#include <hip/hip_runtime.h>
#include <hip/hip_bf16.h>

// B=2, S=2048, D=512, K_routes=64, H=8 (heads irrelevant: k-weighted sum is head-uniform)
#define S_DIM 2048
#define D_DIM 512
#define B_DIM 2
#define K_RT  64

typedef __attribute__((ext_vector_type(8))) short short8;   // 8 bf16 = 4 VGPRs (MFMA A/B frag)
typedef __attribute__((ext_vector_type(4))) float f32x4;    // MFMA C/D frag

static __device__ __forceinline__ float bf16lo_to_f(unsigned u) {
    union { unsigned u; float f; } c; c.u = u << 16; return c.f;
}
static __device__ __forceinline__ float bf16hi_to_f(unsigned u) {
    union { unsigned u; float f; } c; c.u = u & 0xffff0000u; return c.f;
}
static __device__ __forceinline__ unsigned short f_to_bf16(float f) {
    union { float f; unsigned u; } c; c.f = f;
    unsigned u = c.u;
    u += 0x7fffu + ((u >> 16) & 1u);   // RTNE (inputs finite/normal)
    return (unsigned short)(u >> 16);
}
static __device__ __forceinline__ unsigned pk2(float a, float b) {
    return (unsigned)f_to_bf16(a) | ((unsigned)f_to_bf16(b) << 16);
}

// ---------------------------------------------------------------------------
// C = A * B^T, fp32 accumulate via MFMA. A: MxK, B: NxK.
// AF32/BF32: operand is fp32 in global, cast to bf16 during LDS staging.
// OUTF32: write fp32 + bias[n] + residual[m,n]; else write bf16.
// 64x64 block tile, 4 waves each 32x32 (2x2 frags of 16x16x32), BK=32.
#define GBM 64
#define GBN 64
#define GBK 32
#define LROW 40   // padded LDS row (bf16 elems): 80 B stride, 16B-aligned, 2-way alias max (free)

template<bool AF32, bool BF32, bool OUTF32>
__global__ __launch_bounds__(256) void gemm_bt(
    const void* __restrict__ Av, const void* __restrict__ Bv, void* __restrict__ Cv,
    const float* __restrict__ bias, const float* __restrict__ residual,
    int M, int N, int K)
{
    __shared__ unsigned short As[GBM * LROW];
    __shared__ unsigned short Bs[GBN * LROW];

    const int tid  = threadIdx.x;
    const int lane = tid & 63;
    const int wv   = tid >> 6;          // wave 0..3
    const int wm   = (wv & 1) * 32;
    const int wn   = (wv >> 1) * 32;
    const int m0   = blockIdx.y * GBM;
    const int n0   = blockIdx.x * GBN;

    // staging map: 256 threads cover one 64x32 tile; thread owns 8 k-elems
    const int lr = tid >> 2;            // row 0..63
    const int lc = (tid & 3) * 8;       // k offset 0,8,16,24

    const int mi = lane & 15;
    const int kg = lane >> 4;

    f32x4 acc[2][2] = {};

    for (int k0 = 0; k0 < K; k0 += GBK) {
        uint4 apk, bpk;
        if (AF32) {
            const float* A = (const float*)Av;
            const float4 a0 = *(const float4*)(A + (size_t)(m0 + lr) * K + k0 + lc);
            const float4 a1 = *(const float4*)(A + (size_t)(m0 + lr) * K + k0 + lc + 4);
            apk.x = pk2(a0.x, a0.y); apk.y = pk2(a0.z, a0.w);
            apk.z = pk2(a1.x, a1.y); apk.w = pk2(a1.z, a1.w);
        } else {
            const unsigned short* A = (const unsigned short*)Av;
            apk = *(const uint4*)(A + (size_t)(m0 + lr) * K + k0 + lc);
        }
        if (BF32) {
            const float* B = (const float*)Bv;
            const float4 b0 = *(const float4*)(B + (size_t)(n0 + lr) * K + k0 + lc);
            const float4 b1 = *(const float4*)(B + (size_t)(n0 + lr) * K + k0 + lc + 4);
            bpk.x = pk2(b0.x, b0.y); bpk.y = pk2(b0.z, b0.w);
            bpk.z = pk2(b1.x, b1.y); bpk.w = pk2(b1.z, b1.w);
        } else {
            const unsigned short* B = (const unsigned short*)Bv;
            bpk = *(const uint4*)(B + (size_t)(n0 + lr) * K + k0 + lc);
        }
        *(uint4*)(As + lr * LROW + lc) = apk;
        *(uint4*)(Bs + lr * LROW + lc) = bpk;
        __syncthreads();

        short8 af0 = *(const short8*)(As + (wm +      mi) * LROW + kg * 8);
        short8 af1 = *(const short8*)(As + (wm + 16 + mi) * LROW + kg * 8);
        short8 bf0 = *(const short8*)(Bs + (wn +      mi) * LROW + kg * 8);
        short8 bf1 = *(const short8*)(Bs + (wn + 16 + mi) * LROW + kg * 8);

        acc[0][0] = __builtin_amdgcn_mfma_f32_16x16x32_bf16(af0, bf0, acc[0][0], 0, 0, 0);
        acc[0][1] = __builtin_amdgcn_mfma_f32_16x16x32_bf16(af0, bf1, acc[0][1], 0, 0, 0);
        acc[1][0] = __builtin_amdgcn_mfma_f32_16x16x32_bf16(af1, bf0, acc[1][0], 0, 0, 0);
        acc[1][1] = __builtin_amdgcn_mfma_f32_16x16x32_bf16(af1, bf1, acc[1][1], 0, 0, 0);
        __syncthreads();
    }

    // C/D layout: col = lane&15, row = (lane>>4)*4 + reg   [verified m89/m91]
    const int rb  = (lane >> 4) * 4;
    const int col = lane & 15;
    #pragma unroll
    for (int i = 0; i < 2; ++i) {
        #pragma unroll
        for (int j = 0; j < 2; ++j) {
            #pragma unroll
            for (int r = 0; r < 4; ++r) {
                const int m = m0 + wm + i * 16 + rb + r;
                const int n = n0 + wn + j * 16 + col;
                const float v = acc[i][j][r];
                if (OUTF32) {
                    ((float*)Cv)[(size_t)m * N + n] = v + bias[n] + residual[(size_t)m * N + n];
                } else {
                    ((unsigned short*)Cv)[(size_t)m * N + n] = f_to_bf16(v);
                }
            }
        }
    }
}

// ---------------------------------------------------------------------------
// fused[b,s,:] = sum_k softmax_k(-dist[s,routes[s,k]]) * h[b,routes[s,k],:]
// One wave per (b,s): lane k owns route_k/w_k (in-register softmax); k-loop
// broadcasts via __shfl, 64 lanes read one 1 KB bf16 row coalesced (16 B/lane).
__global__ __launch_bounds__(256) void fuse_gather(
    const unsigned short* __restrict__ h, const int* __restrict__ routes,
    const float* __restrict__ distances, unsigned short* __restrict__ fused)
{
    const int tid  = threadIdx.x;
    const int lane = tid & 63;
    const int wv   = tid >> 6;
    const int s    = blockIdx.x * 4 + wv;
    const int b    = blockIdx.y;

    const int rt = routes[s * K_RT + lane];
    const float v = -distances[(size_t)s * S_DIM + rt];
    float mx = v;
    #pragma unroll
    for (int off = 32; off >= 1; off >>= 1) mx = fmaxf(mx, __shfl_xor(mx, off, 64));
    const float e = __expf(v - mx);
    float sum = e;
    #pragma unroll
    for (int off = 32; off >= 1; off >>= 1) sum += __shfl_xor(sum, off, 64);
    const float wl = e / sum;

    const unsigned short* hb = h + (size_t)b * S_DIM * D_DIM;
    float acc[8] = {};
    #pragma unroll 4
    for (int k = 0; k < 64; ++k) {
        const int   rk = __shfl(rt, k, 64);
        const float wk = __shfl(wl, k, 64);
        const uint4 p = *(const uint4*)(hb + (size_t)rk * D_DIM + lane * 8);
        acc[0] = fmaf(wk, bf16lo_to_f(p.x), acc[0]);
        acc[1] = fmaf(wk, bf16hi_to_f(p.x), acc[1]);
        acc[2] = fmaf(wk, bf16lo_to_f(p.y), acc[2]);
        acc[3] = fmaf(wk, bf16hi_to_f(p.y), acc[3]);
        acc[4] = fmaf(wk, bf16lo_to_f(p.z), acc[4]);
        acc[5] = fmaf(wk, bf16hi_to_f(p.z), acc[5]);
        acc[6] = fmaf(wk, bf16lo_to_f(p.w), acc[6]);
        acc[7] = fmaf(wk, bf16hi_to_f(p.w), acc[7]);
    }
    uint4 o;
    o.x = pk2(acc[0], acc[1]);
    o.y = pk2(acc[2], acc[3]);
    o.z = pk2(acc[4], acc[5]);
    o.w = pk2(acc[6], acc[7]);
    *(uint4*)(fused + ((size_t)b * S_DIM + s) * D_DIM + lane * 8) = o;
}

// ---------------------------------------------------------------------------
extern "C" void kernel_launch(void* const* d_in, const int* in_sizes, int n_in,
                              void* d_out, int out_size, void* d_ws, size_t ws_size,
                              hipStream_t stream) {
    const float* x         = (const float*)d_in[0];
    const int*   routes    = (const int*)  d_in[1];
    const float* distances = (const float*)d_in[2];
    const float* W_in      = (const float*)d_in[3];
    const float* W_out     = (const float*)d_in[4];
    const float* b_out     = (const float*)d_in[5];
    float* out = (float*)d_out;

    const int M = B_DIM * S_DIM;   // 4096

    // ws layout (bf16 elems): h 2M | fused 2M  = 8 MB
    unsigned short* hb = (unsigned short*)d_ws;
    unsigned short* fb = hb + (size_t)M * D_DIM;

    const dim3 ggrid(D_DIM / GBN, M / GBM);   // 8 x 64

    // 1. h = x @ W_in^T  (fp32 in, inline cast, bf16 out)
    gemm_bt<true, true, false><<<ggrid, 256, 0, stream>>>(
        x, W_in, hb, nullptr, nullptr, M, D_DIM, D_DIM);
    // 2. softmax + gather + weighted sum (bf16 out)
    fuse_gather<<<dim3(S_DIM / 4, B_DIM), 256, 0, stream>>>(hb, routes, distances, fb);
    // 3. out = fused @ W_out^T + b_out + x  (fp32 out + residual)
    gemm_bt<false, true, true><<<ggrid, 256, 0, stream>>>(
        fb, W_out, out, b_out, x, M, D_DIM, D_DIM);
}